// Round 10
// baseline (2355.324 us; speedup 1.0000x reference)
//
#include <hip/hip_runtime.h>

#define N_NODES 50000
#define N_EDGES 800000
#define D 128
#define ED 64
#define NLAYERS 3

typedef __attribute__((ext_vector_type(8))) short s16x8;
typedef __attribute__((ext_vector_type(4))) float f32x4;
#define MFMA16 __builtin_amdgcn_mfma_f32_16x16x32_bf16

__device__ __forceinline__ unsigned short f2bf(float f) {
    unsigned int u = __float_as_uint(f);
    unsigned int r = (u + 0x7FFFu + ((u >> 16) & 1u)) >> 16;
    return (unsigned short)r;
}
__device__ __forceinline__ float bf2f(unsigned short h) {
    return __uint_as_float(((unsigned int)h) << 16);
}

// ---------------- prep kernels ----------------

__global__ void hist_kernel(const int* __restrict__ dst, int* __restrict__ deg) {
    int e = blockIdx.x * blockDim.x + threadIdx.x;
    if (e < N_EDGES) atomicAdd(&deg[dst[e]], 1);
}

__global__ void scan_kernel(int* __restrict__ deg_cursor, int* __restrict__ row_start) {
    __shared__ int part[1024];
    const int t = threadIdx.x;
    const int CH = (N_NODES + 1023) / 1024;  // 49
    int a = t * CH;
    int b = min(a + CH, N_NODES);
    int s = 0;
    for (int i = a; i < b; ++i) s += deg_cursor[i];
    part[t] = s;
    __syncthreads();
    for (int off = 1; off < 1024; off <<= 1) {
        int v = (t >= off) ? part[t - off] : 0;
        __syncthreads();
        part[t] += v;
        __syncthreads();
    }
    int base = (t == 0) ? 0 : part[t - 1];
    for (int i = a; i < b; ++i) {
        int d = deg_cursor[i];
        row_start[i] = base;
        deg_cursor[i] = base;
        base += d;
    }
    if (t == 1023) row_start[N_NODES] = part[1023];
}

__global__ void scatter_kernel(const int* __restrict__ dst, int* __restrict__ cursor,
                               int* __restrict__ perm) {
    int e = blockIdx.x * blockDim.x + threadIdx.x;
    if (e < N_EDGES) {
        int pos = atomicAdd(&cursor[dst[e]], 1);
        perm[pos] = e;
    }
}

// reorder src/dst (always) and optionally edge_attr into dst-sorted order
__global__ void reorder_kernel(const float4* __restrict__ ea, const int* __restrict__ perm,
                               const int* __restrict__ src, const int* __restrict__ dst,
                               float4* __restrict__ ea_d, int* __restrict__ srcd,
                               int* __restrict__ dstd) {
    int idx = blockIdx.x * blockDim.x + threadIdx.x;
    int i = idx >> 2, q = idx & 3;
    if (i < N_EDGES) {
        int pe = perm[i];
        if (ea_d) {
            const float4* srow = ea + (size_t)pe * (ED / 4);
            float4* drow = ea_d + (size_t)i * (ED / 4);
            #pragma unroll
            for (int j = 0; j < 4; ++j) drow[q * 4 + j] = srow[q * 4 + j];
        }
        if (q == 0) { srcd[i] = src[pe]; dstd[i] = dst[pe]; }
    }
}

// We[L][64][128] -> transposed bf16 hi/lo WT[L][128][64]
__global__ void wconv_kernel(const float* __restrict__ We,
                             unsigned short* __restrict__ WThi,
                             unsigned short* __restrict__ WTlo) {
    int idx = blockIdx.x * 256 + threadIdx.x;
    if (idx < NLAYERS * ED * D) {
        int l = idx / (ED * D);
        int rem = idx % (ED * D);
        int k = rem / D, c = rem % D;
        float f = We[idx];
        unsigned short h = f2bf(f);
        unsigned short lo = f2bf(f - bf2f(h));
        int o = (l * D + c) * ED + k;
        WThi[o] = h; WTlo[o] = lo;
    }
}

// ---------------- fused edge pass: msg GEMM (MFMA) + relu(x[src]+msg) + segmented agg ----------------
// Block = 128 dst-sorted edges. Stage ea as bf16 hi/lo in LDS (aliased inside
// sAgg), 3-MFMA fp32-split GEMM, epilogue gathers x[src][col], relu, then
// ds-atomicAdd into sAgg[rank][col] (rank = within-block segment id via wave
// shuffle-scan). Flush: complete segments -> direct store x+agg; boundary
// segments (<=2/block) -> global atomicAdd onto hpre pre-initialized to x.

template<int DIRECT>
__global__ __launch_bounds__(256, 2)
void edge_fused_kernel(const float* __restrict__ x,
                       const float* __restrict__ eaA,
                       const int* __restrict__ srcA,
                       const int* __restrict__ dstA,
                       const int* __restrict__ permN,
                       const unsigned short* __restrict__ WThi,
                       const unsigned short* __restrict__ WTlo,
                       const float* __restrict__ be,
                       float* __restrict__ hpre)
{
    __shared__ float sAgg[128 * 132];            // 67.6 KB; staging aliased inside
    __shared__ int sSrc[128], sDst[128], sFlag[128], sRank[128], sNode[128], sMisc[4];
    unsigned short* sAhi = (unsigned short*)sAgg;              // 18 KB
    unsigned short* sAlo = ((unsigned short*)sAgg) + 128 * 72; // next 18 KB

    const int t  = threadIdx.x;
    const int e0 = blockIdx.x * 128;

    // ---- stage: thread t -> edge el = t>>1, k-half (t&1)*32 ----
    {
        const int el = t >> 1, k0 = (t & 1) * 32;
        const int ge = e0 + el;
        const int pe = DIRECT ? ge : permN[ge];
        if ((t & 1) == 0) { sSrc[el] = srcA[pe]; sDst[el] = dstA[pe]; }
        const float4* s4 = (const float4*)&eaA[(size_t)pe * ED + k0];
        #pragma unroll
        for (int j = 0; j < 4; ++j) {
            float4 va = s4[j * 2], vb = s4[j * 2 + 1];
            float f[8] = {va.x, va.y, va.z, va.w, vb.x, vb.y, vb.z, vb.w};
            s16x8 vh, vl;
            #pragma unroll
            for (int q = 0; q < 8; ++q) {
                unsigned short h = f2bf(f[q]);
                vh[q] = (short)h;
                vl[q] = (short)f2bf(f[q] - bf2f(h));
            }
            *(s16x8*)&sAhi[(t >> 1) * 72 + k0 + j * 8] = vh;
            *(s16x8*)&sAlo[(t >> 1) * 72 + k0 + j * 8] = vl;
        }
    }
    __syncthreads();

    const int w = t >> 6, l = t & 63;
    const int li = l & 15, lk = l >> 4;
    const int erow0 = w * 32;

    // ---- A-frags to registers (staging LDS dead after this) + flags ----
    s16x8 Ah[2][2], Al[2][2];
    #pragma unroll
    for (int r = 0; r < 2; ++r)
        #pragma unroll
        for (int s = 0; s < 2; ++s) {
            int edge = erow0 + r * 16 + li;
            Ah[r][s] = *(const s16x8*)&sAhi[edge * 72 + s * 32 + lk * 8];
            Al[r][s] = *(const s16x8*)&sAlo[edge * 72 + s * 32 + lk * 8];
        }
    if (t < 128) sFlag[t] = (t == 0) ? 1 : (sDst[t] != sDst[t - 1] ? 1 : 0);
    if (t == 0) {
        int pd = -1, nd = -1;
        if (e0 > 0)            pd = DIRECT ? dstA[e0 - 1]   : dstA[permN[e0 - 1]];
        if (e0 + 128 < N_EDGES) nd = DIRECT ? dstA[e0 + 128] : dstA[permN[e0 + 128]];
        sMisc[1] = (e0 == 0            || pd != sDst[0])   ? 1 : 0;  // first segment complete at left
        sMisc[2] = (e0 + 128 >= N_EDGES || nd != sDst[127]) ? 1 : 0;  // last segment complete at right
    }
    __syncthreads();

    // ---- zero agg + rank scan (wave 0) ----
    {
        float4* z = (float4*)sAgg;
        for (int i = t; i < 128 * 132 / 4; i += 256) z[i] = make_float4(0.f, 0.f, 0.f, 0.f);
    }
    if (t < 64) {
        int v0 = sFlag[t], v1 = sFlag[t + 64];
        #pragma unroll
        for (int d = 1; d < 64; d <<= 1) {
            int y0 = __shfl_up(v0, d); if (l >= d) v0 += y0;
        }
        int tot0 = __shfl(v0, 63);
        #pragma unroll
        for (int d = 1; d < 64; d <<= 1) {
            int y1 = __shfl_up(v1, d); if (l >= d) v1 += y1;
        }
        sRank[t] = v0 - 1;
        sRank[t + 64] = tot0 + v1 - 1;
        if (l == 63) sMisc[0] = tot0 + v1;   // nloc
    }
    __syncthreads();
    if (t < 128 && sFlag[t]) sNode[sRank[t]] = sDst[t];
    __syncthreads();

    // ---- GEMM + epilogue: per col-tile c, 6 MFMA then relu(x[src]+msg) -> sAgg ----
    #pragma unroll
    for (int c = 0; c < 8; ++c) {
        const int col = c * 16 + li;
        f32x4 acc0 = {0.f, 0.f, 0.f, 0.f}, acc1 = {0.f, 0.f, 0.f, 0.f};
        #pragma unroll
        for (int s = 0; s < 2; ++s) {
            const s16x8 Bh = *(const s16x8*)&WThi[col * ED + s * 32 + lk * 8];
            const s16x8 Bl = *(const s16x8*)&WTlo[col * ED + s * 32 + lk * 8];
            acc0 = MFMA16(Ah[0][s], Bh, acc0, 0, 0, 0);
            acc1 = MFMA16(Ah[1][s], Bh, acc1, 0, 0, 0);
            acc0 = MFMA16(Ah[0][s], Bl, acc0, 0, 0, 0);
            acc1 = MFMA16(Ah[1][s], Bl, acc1, 0, 0, 0);
            acc0 = MFMA16(Al[0][s], Bh, acc0, 0, 0, 0);
            acc1 = MFMA16(Al[1][s], Bh, acc1, 0, 0, 0);
        }
        const float bias = be[col];
        #pragma unroll
        for (int reg = 0; reg < 4; ++reg) {
            const int el0 = erow0 + lk * 4 + reg;        // D map: col=lane&15, row=(lane>>4)*4+reg
            const int el1 = el0 + 16;
            float v0 = fmaxf(acc0[reg] + bias + x[(size_t)sSrc[el0] * D + col], 0.f);
            float v1 = fmaxf(acc1[reg] + bias + x[(size_t)sSrc[el1] * D + col], 0.f);
            atomicAdd(&sAgg[sRank[el0] * 132 + col], v0);
            atomicAdd(&sAgg[sRank[el1] * 132 + col], v1);
        }
    }
    __syncthreads();

    // ---- flush segments ----
    const int nloc = sMisc[0], firstc = sMisc[1], lastc = sMisc[2];
    for (int idx = t; idx < nloc * 64; idx += 256) {
        const int r = idx >> 6, cp = idx & 63, col = cp * 2;
        const int node = sNode[r];
        const float a0 = sAgg[r * 132 + col], a1 = sAgg[r * 132 + col + 1];
        const size_t o = (size_t)node * D + col;
        const bool comp = (r > 0 || firstc) && (r < nloc - 1 || lastc);
        if (comp) {
            float2 xv = *(const float2*)&x[o];
            float2 ov = make_float2(a0 + xv.x, a1 + xv.y);
            *(float2*)&hpre[o] = ov;
        } else {
            atomicAdd(&hpre[o], a0);
            atomicAdd(&hpre[o + 1], a1);
        }
    }
}

// ---------------- MLP GEMM: out = [relu](in @ W + b) ----------------

__global__ __launch_bounds__(256, 3)
void mlp_kernel(const float* __restrict__ in,
                const float* __restrict__ W,
                const float* __restrict__ bias,
                float* __restrict__ out,
                int do_relu)
{
    __shared__ float sWh[64][D];
    __shared__ float sIn[64][68];

    const int t  = threadIdx.x;
    const int n0 = blockIdx.x * 64;
    const int r0 = (t >> 5) * 8;
    const int c0 = (t & 31) * 4;

    float acc[8][4];
    #pragma unroll
    for (int e = 0; e < 8; ++e)
        #pragma unroll
        for (int j = 0; j < 4; ++j) acc[e][j] = 0.f;

    for (int k0 = 0; k0 < D; k0 += 64) {
        __syncthreads();
        {
            const float4* w4 = (const float4*)W;
            #pragma unroll
            for (int i = 0; i < 8; ++i) {
                int idx = t + i * 256;
                int kl = idx >> 5, c4 = idx & 31;
                *(float4*)&sWh[kl][c4 * 4] = w4[(size_t)(k0 + kl) * 32 + c4];
            }
        }
        {
            int r = t & 63, prt = t >> 6;
            int gr = n0 + r;
            #pragma unroll
            for (int q = 0; q < 4; ++q) {
                float4 v = make_float4(0.f, 0.f, 0.f, 0.f);
                if (gr < N_NODES) v = ((const float4*)&in[(size_t)gr * D])[(k0 >> 2) + prt * 4 + q];
                int kl = prt * 16 + q * 4;
                sIn[kl + 0][r] = v.x;
                sIn[kl + 1][r] = v.y;
                sIn[kl + 2][r] = v.z;
                sIn[kl + 3][r] = v.w;
            }
        }
        __syncthreads();

        #pragma unroll 8
        for (int kl = 0; kl < 64; ++kl) {
            float4 b4 = *(const float4*)&sWh[kl][c0];
            float4 a0 = *(const float4*)&sIn[kl][r0];
            float4 a1 = *(const float4*)&sIn[kl][r0 + 4];
            float av[8] = {a0.x, a0.y, a0.z, a0.w, a1.x, a1.y, a1.z, a1.w};
            float bv[4] = {b4.x, b4.y, b4.z, b4.w};
            #pragma unroll
            for (int e = 0; e < 8; ++e)
                #pragma unroll
                for (int j = 0; j < 4; ++j)
                    acc[e][j] = fmaf(av[e], bv[j], acc[e][j]);
        }
    }

    float4 bb = *(const float4*)&bias[c0];
    #pragma unroll
    for (int e = 0; e < 8; ++e) {
        int gr = n0 + r0 + e;
        if (gr < N_NODES) {
            float4 o;
            o.x = acc[e][0] + bb.x;
            o.y = acc[e][1] + bb.y;
            o.z = acc[e][2] + bb.z;
            o.w = acc[e][3] + bb.w;
            if (do_relu) {
                o.x = fmaxf(o.x, 0.f); o.y = fmaxf(o.y, 0.f);
                o.z = fmaxf(o.z, 0.f); o.w = fmaxf(o.w, 0.f);
            }
            *(float4*)&out[(size_t)gr * D + c0] = o;
        }
    }
}

// ---------------- host ----------------

extern "C" void kernel_launch(void* const* d_in, const int* in_sizes, int n_in,
                              void* d_out, int out_size, void* d_ws, size_t ws_size,
                              hipStream_t stream) {
    const float* x  = (const float*)d_in[0];
    const int*   ei = (const int*)d_in[1];
    const float* ea = (const float*)d_in[2];
    const float* We = (const float*)d_in[3];
    const float* be = (const float*)d_in[4];
    const float* W1 = (const float*)d_in[5];
    const float* b1 = (const float*)d_in[6];
    const float* W2 = (const float*)d_in[7];
    const float* b2 = (const float*)d_in[8];
    float* out = (float*)d_out;

    const int* src = ei;
    const int* dst = ei + N_EDGES;

    char* ws = (char*)d_ws;
    size_t off = 0;
    auto alloc = [&](size_t bytes) -> char* {
        char* p = ws + off;
        off = (off + bytes + 255) & ~(size_t)255;
        return p;
    };
    float* P          = (float*)alloc((size_t)N_NODES * D * 4);
    float* T          = (float*)alloc((size_t)N_NODES * D * 4);
    float* H          = (float*)alloc((size_t)N_NODES * D * 4);
    int*   perm       = (int*)alloc((size_t)N_EDGES * 4);
    int*   row_start  = (int*)alloc((size_t)(N_NODES + 1) * 4);
    int*   cursor     = (int*)alloc((size_t)N_NODES * 4);
    int*   srcd       = (int*)alloc((size_t)N_EDGES * 4);
    int*   dstd       = (int*)alloc((size_t)N_EDGES * 4);
    unsigned short* WThi = (unsigned short*)alloc((size_t)NLAYERS * D * ED * 2);
    unsigned short* WTlo = (unsigned short*)alloc((size_t)NLAYERS * D * ED * 2);
    float* ea_d = (float*)alloc((size_t)N_EDGES * ED * 4);
    const bool direct = (off <= ws_size);
    if (!direct) ea_d = nullptr;
    (void)in_sizes; (void)n_in; (void)out_size;

    // build dst-sorted CSR + reordered arrays
    hipMemsetAsync(cursor, 0, N_NODES * 4, stream);
    hist_kernel<<<(N_EDGES + 255) / 256, 256, 0, stream>>>(dst, cursor);
    scan_kernel<<<1, 1024, 0, stream>>>(cursor, row_start);
    scatter_kernel<<<(N_EDGES + 255) / 256, 256, 0, stream>>>(dst, cursor, perm);
    reorder_kernel<<<(N_EDGES * 4 + 255) / 256, 256, 0, stream>>>(
        (const float4*)ea, perm, src, dst, (float4*)ea_d, srcd, dstd);
    wconv_kernel<<<(NLAYERS * ED * D + 255) / 256, 256, 0, stream>>>(We, WThi, WTlo);

    const int ggrid = N_EDGES / 128;             // 6250
    const int mgrid = (N_NODES + 63) / 64;       // 782

    const float* X = x;
    for (int l = 0; l < NLAYERS; ++l) {
        const unsigned short* wh = WThi + (size_t)l * D * ED;
        const unsigned short* wl = WTlo + (size_t)l * D * ED;
        const float* bel = be + (size_t)l * D;
        // hpre starts as x (identity term + landing pad for boundary atomics)
        hipMemcpyAsync(P, (const void*)X, (size_t)N_NODES * D * 4,
                       hipMemcpyDeviceToDevice, stream);
        if (direct)
            edge_fused_kernel<1><<<ggrid, 256, 0, stream>>>(X, ea_d, srcd, dstd, nullptr, wh, wl, bel, P);
        else
            edge_fused_kernel<0><<<ggrid, 256, 0, stream>>>(X, ea, src, dst, perm, wh, wl, bel, P);
        mlp_kernel<<<mgrid, 256, 0, stream>>>(P, W1 + (size_t)l * D * D, b1 + (size_t)l * D, T, 1);
        float* ob = (l < NLAYERS - 1) ? H : out;
        mlp_kernel<<<mgrid, 256, 0, stream>>>(T, W2 + (size_t)l * D * D, b2 + (size_t)l * D, ob,
                                              (l < NLAYERS - 1) ? 1 : 0);
        X = H;
    }
}

// Round 11
// 1419.722 us; speedup vs baseline: 1.6590x; 1.6590x over previous
//
#include <hip/hip_runtime.h>
#include <hip/hip_fp16.h>

#define N_NODES 50000
#define N_EDGES 800000
#define D 128
#define ED 64
#define NLAYERS 3

typedef __attribute__((ext_vector_type(8))) short s16x8;
typedef __attribute__((ext_vector_type(4))) float f32x4;
#define MFMA16 __builtin_amdgcn_mfma_f32_16x16x32_bf16

__device__ __forceinline__ unsigned short f2bf(float f) {
    unsigned int u = __float_as_uint(f);
    unsigned int r = (u + 0x7FFFu + ((u >> 16) & 1u)) >> 16;
    return (unsigned short)r;
}
__device__ __forceinline__ float bf2f(unsigned short h) {
    return __uint_as_float(((unsigned int)h) << 16);
}

// ---------------- prep kernels ----------------

__global__ void hist_kernel(const int* __restrict__ dst, int* __restrict__ deg) {
    int e = blockIdx.x * blockDim.x + threadIdx.x;
    if (e < N_EDGES) atomicAdd(&deg[dst[e]], 1);
}

__global__ void scan_kernel(int* __restrict__ deg_cursor, int* __restrict__ row_start) {
    __shared__ int part[1024];
    const int t = threadIdx.x;
    const int CH = (N_NODES + 1023) / 1024;  // 49
    int a = t * CH;
    int b = min(a + CH, N_NODES);
    int s = 0;
    for (int i = a; i < b; ++i) s += deg_cursor[i];
    part[t] = s;
    __syncthreads();
    for (int off = 1; off < 1024; off <<= 1) {
        int v = (t >= off) ? part[t - off] : 0;
        __syncthreads();
        part[t] += v;
        __syncthreads();
    }
    int base = (t == 0) ? 0 : part[t - 1];
    for (int i = a; i < b; ++i) {
        int d = deg_cursor[i];
        row_start[i] = base;
        deg_cursor[i] = base;
        base += d;
    }
    if (t == 1023) row_start[N_NODES] = part[1023];
}

__global__ void scatter_kernel(const int* __restrict__ dst, int* __restrict__ cursor,
                               int* __restrict__ perm) {
    int e = blockIdx.x * blockDim.x + threadIdx.x;
    if (e < N_EDGES) {
        int pos = atomicAdd(&cursor[dst[e]], 1);
        perm[pos] = e;
    }
}

// reorder src (always) and optionally edge_attr into dst-sorted order
__global__ void reorder_kernel(const float4* __restrict__ ea, const int* __restrict__ perm,
                               const int* __restrict__ src,
                               float4* __restrict__ ea_d, int* __restrict__ srcd) {
    int idx = blockIdx.x * blockDim.x + threadIdx.x;
    int i = idx >> 2, q = idx & 3;
    if (i < N_EDGES) {
        int pe = perm[i];
        if (ea_d) {
            const float4* srow = ea + (size_t)pe * (ED / 4);
            float4* drow = ea_d + (size_t)i * (ED / 4);
            #pragma unroll
            for (int j = 0; j < 4; ++j) drow[q * 4 + j] = srow[q * 4 + j];
        }
        if (q == 0) srcd[i] = src[pe];
    }
}

// Wsrc[L][K][C] -> transposed bf16 hi/lo T[L][C][K]
__global__ void wconvT_kernel(const float* __restrict__ Wsrc,
                              unsigned short* __restrict__ Thi,
                              unsigned short* __restrict__ Tlo,
                              int L, int K, int C) {
    int idx = blockIdx.x * 256 + threadIdx.x;
    if (idx < L * K * C) {
        int l = idx / (K * C);
        int rem = idx % (K * C);
        int k = rem / C, c = rem % C;
        float f = Wsrc[idx];
        unsigned short h = f2bf(f);
        unsigned short lo = f2bf(f - bf2f(h));
        int o = (l * C + c) * K + k;
        Thi[o] = h; Tlo[o] = lo;
    }
}

// ---------------- edge GEMM (MFMA): msg[e] = ea_d[e] @ We + be  (fp16 out) ----------------
// 128 edges/block, 4 waves; A staged in LDS bf16 hi/lo (rows padded to 72),
// B (WeT) L1-resident from global. fp32 ~= hi*hi + hi*lo + lo*hi.

template<int DIRECT>
__global__ __launch_bounds__(256, 3)
void edge_gemm_kernel(const float* __restrict__ eaA,
                      const int* __restrict__ permN,
                      const unsigned short* __restrict__ WThi,
                      const unsigned short* __restrict__ WTlo,
                      const float* __restrict__ be,
                      __half* __restrict__ msgh)
{
    __shared__ unsigned short sAhi[128 * 72];
    __shared__ unsigned short sAlo[128 * 72];
    const int t = threadIdx.x;
    const int e0 = blockIdx.x * 128;

    {
        const int el = t >> 1, k0 = (t & 1) * 32;
        int ge = e0 + el;
        if (!DIRECT) ge = permN[ge];
        const float4* s4 = (const float4*)&eaA[(size_t)ge * ED + k0];
        #pragma unroll
        for (int j = 0; j < 4; ++j) {
            float4 va = s4[j * 2], vb = s4[j * 2 + 1];
            float f[8] = {va.x, va.y, va.z, va.w, vb.x, vb.y, vb.z, vb.w};
            s16x8 vh, vl;
            #pragma unroll
            for (int q = 0; q < 8; ++q) {
                unsigned short h = f2bf(f[q]);
                vh[q] = (short)h;
                vl[q] = (short)f2bf(f[q] - bf2f(h));
            }
            *(s16x8*)&sAhi[el * 72 + k0 + j * 8] = vh;
            *(s16x8*)&sAlo[el * 72 + k0 + j * 8] = vl;
        }
    }
    __syncthreads();

    const int w = t >> 6, l = t & 63;
    const int li = l & 15, lk = l >> 4;
    const int erow0 = w * 32;

    s16x8 Ah[2][2], Al[2][2];
    #pragma unroll
    for (int r = 0; r < 2; ++r)
        #pragma unroll
        for (int s = 0; s < 2; ++s) {
            int edge = erow0 + r * 16 + li;
            Ah[r][s] = *(const s16x8*)&sAhi[edge * 72 + s * 32 + lk * 8];
            Al[r][s] = *(const s16x8*)&sAlo[edge * 72 + s * 32 + lk * 8];
        }

    #pragma unroll
    for (int c = 0; c < 8; ++c) {
        const int col = c * 16 + li;
        f32x4 acc0 = {0.f, 0.f, 0.f, 0.f}, acc1 = {0.f, 0.f, 0.f, 0.f};
        #pragma unroll
        for (int s = 0; s < 2; ++s) {
            const s16x8 Bh = *(const s16x8*)&WThi[col * ED + s * 32 + lk * 8];
            const s16x8 Bl = *(const s16x8*)&WTlo[col * ED + s * 32 + lk * 8];
            acc0 = MFMA16(Ah[0][s], Bh, acc0, 0, 0, 0);
            acc1 = MFMA16(Ah[1][s], Bh, acc1, 0, 0, 0);
            acc0 = MFMA16(Ah[0][s], Bl, acc0, 0, 0, 0);
            acc1 = MFMA16(Ah[1][s], Bl, acc1, 0, 0, 0);
            acc0 = MFMA16(Al[0][s], Bh, acc0, 0, 0, 0);
            acc1 = MFMA16(Al[1][s], Bh, acc1, 0, 0, 0);
        }
        const float bias = be[col];
        // D map [m89-verified]: col = lane&15, row = (lane>>4)*4 + reg
        #pragma unroll
        for (int reg = 0; reg < 4; ++reg) {
            size_t r0i = (size_t)(e0 + erow0 + lk * 4 + reg) * D + col;
            size_t r1i = (size_t)(e0 + erow0 + 16 + lk * 4 + reg) * D + col;
            msgh[r0i] = __float2half(acc0[reg] + bias);
            msgh[r1i] = __float2half(acc1[reg] + bias);
        }
    }
}

// ---------------- segmented reduce: hpre[n] = x[n] + sum relu(x[src]+msg) ----------------

__global__ __launch_bounds__(256, 8)
void seg_reduce_kernel(const float* __restrict__ x,
                       const __half* __restrict__ msgh,
                       const int* __restrict__ srcd,
                       const int* __restrict__ row_start,
                       float* __restrict__ hpre,
                       int nranges, int epw)
{
    const int t = threadIdx.x, lane = t & 63;
    const int rid = (blockIdx.x * 256 + t) >> 6;
    if (rid >= nranges) return;
    const int c0 = lane * 2;

    int lo_t = min(rid * epw, N_EDGES);
    int hi_t = min((rid + 1) * epw, N_EDGES);
    int n_lo, n_hi;
    { int a = 0, b = N_NODES;
      while (a < b) { int m = (a + b) >> 1; if (row_start[m] < lo_t) a = m + 1; else b = m; }
      n_lo = a; }
    if (rid == nranges - 1) {
        n_hi = N_NODES;
    } else {
        int a = 0, b = N_NODES;
        while (a < b) { int m = (a + b) >> 1; if (row_start[m] < hi_t) a = m + 1; else b = m; }
        n_hi = a;
    }

    for (int n = n_lo; n < n_hi; ++n) {
        float2 acc = *(const float2*)&x[(size_t)n * D + c0];   // (1+eps)*x, eps=0
        const int ebeg = row_start[n], eend = row_start[n + 1];
        for (int e = ebeg; e < eend; ++e) {
            __half2 mh = *(const __half2*)&msgh[(size_t)e * D + c0];
            float2 m = __half22float2(mh);
            float2 xs = *(const float2*)&x[(size_t)srcd[e] * D + c0];
            acc.x += fmaxf(m.x + xs.x, 0.f);
            acc.y += fmaxf(m.y + xs.y, 0.f);
        }
        *(float2*)&hpre[(size_t)n * D + c0] = acc;
    }
}

// ---------------- MLP GEMM (MFMA): out = [relu](in @ W + b) ----------------
// 64 rows/block, 4 waves x 16 rows, K=128, N=128. In-kernel fp32->bf16 hi/lo
// staging (rows padded to 136); WT (transposed hi/lo) L1/L2-resident.

__global__ __launch_bounds__(256, 4)
void mlp_mfma_kernel(const float* __restrict__ in,
                     const unsigned short* __restrict__ WThi,
                     const unsigned short* __restrict__ WTlo,
                     const float* __restrict__ bias,
                     float* __restrict__ out,
                     int do_relu)
{
    __shared__ unsigned short sIhi[64 * 136];
    __shared__ unsigned short sIlo[64 * 136];
    const int t = threadIdx.x;
    const int n0 = blockIdx.x * 64;

    // stage: thread t -> row t>>2, k-quarter (t&3)*32
    {
        const int r = t >> 2, k0 = (t & 3) * 32;
        const int gr = n0 + r;
        #pragma unroll
        for (int j = 0; j < 4; ++j) {
            s16x8 vh = {0,0,0,0,0,0,0,0}, vl = {0,0,0,0,0,0,0,0};
            if (gr < N_NODES) {
                const float4* s4 = (const float4*)&in[(size_t)gr * D + k0];
                float4 va = s4[j * 2], vb = s4[j * 2 + 1];
                float f[8] = {va.x, va.y, va.z, va.w, vb.x, vb.y, vb.z, vb.w};
                #pragma unroll
                for (int q = 0; q < 8; ++q) {
                    unsigned short h = f2bf(f[q]);
                    vh[q] = (short)h;
                    vl[q] = (short)f2bf(f[q] - bf2f(h));
                }
            }
            *(s16x8*)&sIhi[r * 136 + k0 + j * 8] = vh;
            *(s16x8*)&sIlo[r * 136 + k0 + j * 8] = vl;
        }
    }
    __syncthreads();

    const int w = t >> 6, l = t & 63;
    const int li = l & 15, lk = l >> 4;
    const int row0 = w * 16;

    s16x8 Ah[4], Al[4];
    #pragma unroll
    for (int s = 0; s < 4; ++s) {
        Ah[s] = *(const s16x8*)&sIhi[(row0 + li) * 136 + s * 32 + lk * 8];
        Al[s] = *(const s16x8*)&sIlo[(row0 + li) * 136 + s * 32 + lk * 8];
    }

    #pragma unroll
    for (int c = 0; c < 8; ++c) {
        const int col = c * 16 + li;
        f32x4 acc = {0.f, 0.f, 0.f, 0.f};
        #pragma unroll
        for (int s = 0; s < 4; ++s) {
            const s16x8 Bh = *(const s16x8*)&WThi[col * D + s * 32 + lk * 8];
            const s16x8 Bl = *(const s16x8*)&WTlo[col * D + s * 32 + lk * 8];
            acc = MFMA16(Ah[s], Bh, acc, 0, 0, 0);
            acc = MFMA16(Ah[s], Bl, acc, 0, 0, 0);
            acc = MFMA16(Al[s], Bh, acc, 0, 0, 0);
        }
        const float bb = bias[col];
        #pragma unroll
        for (int reg = 0; reg < 4; ++reg) {
            const int gr = n0 + row0 + lk * 4 + reg;
            if (gr < N_NODES) {
                float v = acc[reg] + bb;
                if (do_relu) v = fmaxf(v, 0.f);
                out[(size_t)gr * D + col] = v;
            }
        }
    }
}

// ---------------- host ----------------

extern "C" void kernel_launch(void* const* d_in, const int* in_sizes, int n_in,
                              void* d_out, int out_size, void* d_ws, size_t ws_size,
                              hipStream_t stream) {
    const float* x  = (const float*)d_in[0];
    const int*   ei = (const int*)d_in[1];
    const float* ea = (const float*)d_in[2];
    const float* We = (const float*)d_in[3];
    const float* be = (const float*)d_in[4];
    const float* W1 = (const float*)d_in[5];
    const float* b1 = (const float*)d_in[6];
    const float* W2 = (const float*)d_in[7];
    const float* b2 = (const float*)d_in[8];
    float* out = (float*)d_out;

    const int* src = ei;
    const int* dst = ei + N_EDGES;

    char* ws = (char*)d_ws;
    size_t off = 0;
    auto alloc = [&](size_t bytes) -> char* {
        char* p = ws + off;
        off = (off + bytes + 255) & ~(size_t)255;
        return p;
    };
    float* P          = (float*)alloc((size_t)N_NODES * D * 4);
    float* T          = (float*)alloc((size_t)N_NODES * D * 4);
    float* H          = (float*)alloc((size_t)N_NODES * D * 4);
    int*   perm       = (int*)alloc((size_t)N_EDGES * 4);
    int*   row_start  = (int*)alloc((size_t)(N_NODES + 1) * 4);
    int*   cursor     = (int*)alloc((size_t)N_NODES * 4);
    int*   srcd       = (int*)alloc((size_t)N_EDGES * 4);
    unsigned short* WeThi = (unsigned short*)alloc((size_t)NLAYERS * D * ED * 2);
    unsigned short* WeTlo = (unsigned short*)alloc((size_t)NLAYERS * D * ED * 2);
    unsigned short* W1Thi = (unsigned short*)alloc((size_t)NLAYERS * D * D * 2);
    unsigned short* W1Tlo = (unsigned short*)alloc((size_t)NLAYERS * D * D * 2);
    unsigned short* W2Thi = (unsigned short*)alloc((size_t)NLAYERS * D * D * 2);
    unsigned short* W2Tlo = (unsigned short*)alloc((size_t)NLAYERS * D * D * 2);
    __half* msgh = (__half*)alloc((size_t)N_EDGES * D * 2);
    float* ea_d  = (float*)alloc((size_t)N_EDGES * ED * 4);
    bool direct = (off <= ws_size);
    if (!direct) ea_d = nullptr;
    (void)in_sizes; (void)n_in; (void)out_size;

    // build dst-sorted CSR + reordered arrays + weight conversions
    hipMemsetAsync(cursor, 0, N_NODES * 4, stream);
    hist_kernel<<<(N_EDGES + 255) / 256, 256, 0, stream>>>(dst, cursor);
    scan_kernel<<<1, 1024, 0, stream>>>(cursor, row_start);
    scatter_kernel<<<(N_EDGES + 255) / 256, 256, 0, stream>>>(dst, cursor, perm);
    reorder_kernel<<<(N_EDGES * 4 + 255) / 256, 256, 0, stream>>>(
        (const float4*)ea, perm, src, (float4*)ea_d, srcd);
    wconvT_kernel<<<(NLAYERS * ED * D + 255) / 256, 256, 0, stream>>>(We, WeThi, WeTlo, NLAYERS, ED, D);
    wconvT_kernel<<<(NLAYERS * D * D + 255) / 256, 256, 0, stream>>>(W1, W1Thi, W1Tlo, NLAYERS, D, D);
    wconvT_kernel<<<(NLAYERS * D * D + 255) / 256, 256, 0, stream>>>(W2, W2Thi, W2Tlo, NLAYERS, D, D);

    const int ggrid   = N_EDGES / 128;                      // 6250
    const int nranges = 8192;
    const int rblocks = nranges / 4;                        // 2048
    const int epw     = (N_EDGES + nranges - 1) / nranges;  // 98
    const int mgrid   = (N_NODES + 63) / 64;                // 782

    const float* X = x;
    for (int l = 0; l < NLAYERS; ++l) {
        const float* bel = be + (size_t)l * D;
        if (direct)
            edge_gemm_kernel<1><<<ggrid, 256, 0, stream>>>(ea_d, nullptr,
                WeThi + (size_t)l * D * ED, WeTlo + (size_t)l * D * ED, bel, msgh);
        else
            edge_gemm_kernel<0><<<ggrid, 256, 0, stream>>>(ea, perm,
                WeThi + (size_t)l * D * ED, WeTlo + (size_t)l * D * ED, bel, msgh);
        seg_reduce_kernel<<<rblocks, 256, 0, stream>>>(X, msgh, srcd, row_start, P, nranges, epw);
        mlp_mfma_kernel<<<mgrid, 256, 0, stream>>>(P,
            W1Thi + (size_t)l * D * D, W1Tlo + (size_t)l * D * D, b1 + (size_t)l * D, T, 1);
        float* ob = (l < NLAYERS - 1) ? H : out;
        mlp_mfma_kernel<<<mgrid, 256, 0, stream>>>(T,
            W2Thi + (size_t)l * D * D, W2Tlo + (size_t)l * D * D, b2 + (size_t)l * D, ob,
            (l < NLAYERS - 1) ? 1 : 0);
        X = H;
    }
}